// Round 1
// baseline (183.777 us; speedup 1.0000x reference)
//
#include <hip/hip_runtime.h>
#include <hip/hip_bf16.h>

// ScalarDistanceDeepSet: B=32, N=256, pairs P=N*(N-1)/2=32640 (upper tri, k=1)
// phi: s -> relu(s*W1+b1) [64] -> relu(.@W2+b2) [128], masked sum over pairs
// rho: pooled[128] -> relu(@W3+b3)[256] -> relu(@W4+b4)[128] -> @W5+b5 [64]
//
// Key trick: g_e(s) = b2[e] + sum_j W2[j,e]*relu(W1[j]*s+b1[j]) is piecewise
// linear in the scalar s with 64 shared breakpoints t_j = -b1[j]/W1[j].
// Precompute alpha[seg][e], beta[seg][e] for the 65 segments; then per pair:
// find segment (6-step binary search), h2[e] = relu(alpha*s+beta). EXACT
// (same function, different fp32 summation order), ~64x fewer FLOPs.

#define NB 32
#define NN 256
#define PHI2 128
#define SEGS 65

// ---------------- Kernel A: build tables ----------------
// grid: 65 blocks (one per segment), 128 threads (one per output channel e)
__global__ __launch_bounds__(128) void build_tables(
    const float* __restrict__ W1, const float* __restrict__ b1,
    const float* __restrict__ W2, const float* __restrict__ b2,
    float* __restrict__ alpha_g, float* __restrict__ beta_g,
    float* __restrict__ tsort, float* __restrict__ pooled) {
  __shared__ float t_s[64], w1_s[64], b1_s[64];
  __shared__ int cat_s[64], rank_s[64];
  const int tid = threadIdx.x;
  const int seg = blockIdx.x;
  if (tid < 64) {
    float w = W1[tid], bb = b1[tid];
    w1_s[tid] = w; b1_s[tid] = bb;
    int cat; float t;
    if (w > 0.f)      { cat = 0; t = -bb / w; }   // active for s > t
    else if (w < 0.f) { cat = 1; t = -bb / w; }   // active for s < t
    else              { cat = (bb > 0.f) ? 2 : 3; t = 0.f; } // always / never
    t_s[tid] = t; cat_s[tid] = cat;
  }
  __syncthreads();
  if (tid < 64) {
    float t = t_s[tid]; int r = 0;
    for (int k = 0; k < 64; ++k) {
      float tk = t_s[k];
      r += (tk < t) || (tk == t && k < tid);   // stable rank (ties by index)
    }
    rank_s[tid] = r;
    if (seg == 0) tsort[r] = t;
  }
  __syncthreads();
  // e = tid; seg membership: seg(s) = #breakpoints strictly < s.
  // cat0 (w>0): active iff seg > rank ; cat1 (w<0): active iff seg <= rank.
  float a = 0.f, bsum = b2[tid];
  for (int j = 0; j < 64; ++j) {
    int cat = cat_s[j], r = rank_s[j];
    bool act = (cat == 0) ? (seg > r) : (cat == 1) ? (seg <= r) : (cat == 2);
    float w2 = W2[j * PHI2 + tid];
    float m = act ? 1.f : 0.f;
    a    = fmaf(m * w1_s[j], w2, a);
    bsum = fmaf(m * b1_s[j], w2, bsum);
  }
  alpha_g[tid * SEGS + seg] = a;   // e-major layout: [128][65]
  beta_g [tid * SEGS + seg] = bsum;
  if (seg == 0) {
    for (int i = tid; i < NB * PHI2; i += 128) pooled[i] = 0.f;
  }
}

// ---------------- Kernel B: phi + masked pooling ----------------
// grid: (32 row-chunks, 2 e-halves, 32 batches), 256 threads.
// Thread t: ep = t&3 (owns channels e_local = ep+4k, k<16), group g = t>>2
// (pair slot). Each block stages its e-half of the alpha/beta tables in LDS
// (2*4160 floats = 33 KB -> 4 blocks/CU).
__global__ __launch_bounds__(256) void phi_pool(
    const float* __restrict__ dm, const int* __restrict__ lengths,
    const float* __restrict__ alpha_g, const float* __restrict__ beta_g,
    const float* __restrict__ tsort, float* __restrict__ pooled) {
  __shared__ float a_s[64 * SEGS];
  __shared__ float b_s[64 * SEGS];
  __shared__ float t_s[64];
  const int chunk = blockIdx.x;   // 0..31 row stride
  const int ehalf = blockIdx.y;   // 0..1
  const int b     = blockIdx.z;   // batch
  const int tid = threadIdx.x;
  for (int i = tid; i < 64 * SEGS; i += 256) {
    a_s[i] = alpha_g[ehalf * 64 * SEGS + i];
    b_s[i] = beta_g [ehalf * 64 * SEGS + i];
  }
  if (tid < 64) t_s[tid] = tsort[tid];
  __syncthreads();

  const int len = lengths[b];
  const int ep = tid & 3, g = tid >> 2;
  float acc[16];
#pragma unroll
  for (int k = 0; k < 16; ++k) acc[k] = 0.f;

  const float* dmb = dm + (size_t)b * (NN * NN);
  for (int i0 = chunk; i0 <= len - 2; i0 += 32) {
    const float* row = dmb + i0 * NN;
    for (int i1 = i0 + 1 + g; i1 < len; i1 += 64) {
      float s = row[i1];
      // lower_bound over 64 sorted breakpoints: pos = #(t < s)
      int pos = 0;
#pragma unroll
      for (int step = 32; step >= 1; step >>= 1)
        if (t_s[pos + step - 1] < s) pos += step;
#pragma unroll
      for (int k = 0; k < 16; ++k) {
        int idx = (ep + 4 * k) * SEGS + pos;
        acc[k] += fmaxf(fmaf(a_s[idx], s, b_s[idx]), 0.f);
      }
    }
  }
  // reduce over the 16 pair-groups within each wave (lanes sharing bits 0..1)
#pragma unroll
  for (int k = 0; k < 16; ++k) {
    float v = acc[k];
    v += __shfl_xor(v, 4, 64);
    v += __shfl_xor(v, 8, 64);
    v += __shfl_xor(v, 16, 64);
    v += __shfl_xor(v, 32, 64);
    acc[k] = v;
  }
  if ((tid & 63) < 4) {
#pragma unroll
    for (int k = 0; k < 16; ++k)
      atomicAdd(&pooled[b * PHI2 + ehalf * 64 + ep + 4 * k], acc[k]);
  }
}

// ---------------- Kernel C: rho MLP ----------------
// grid: 32 blocks (one per batch), 256 threads
__global__ __launch_bounds__(256) void rho_mlp(
    const float* __restrict__ pooled,
    const float* __restrict__ W3, const float* __restrict__ b3,
    const float* __restrict__ W4, const float* __restrict__ b4,
    const float* __restrict__ W5, const float* __restrict__ b5,
    float* __restrict__ out) {
  __shared__ float p_s[128], r1_s[256], r2_s[128];
  const int b = blockIdx.x, tid = threadIdx.x;
  if (tid < 128) p_s[tid] = pooled[b * 128 + tid];
  __syncthreads();
  {
    float acc = b3[tid];
#pragma unroll 4
    for (int k = 0; k < 128; ++k) acc = fmaf(p_s[k], W3[k * 256 + tid], acc);
    r1_s[tid] = fmaxf(acc, 0.f);
  }
  __syncthreads();
  if (tid < 128) {
    float acc = b4[tid];
#pragma unroll 4
    for (int k = 0; k < 256; ++k) acc = fmaf(r1_s[k], W4[k * 128 + tid], acc);
    r2_s[tid] = fmaxf(acc, 0.f);
  }
  __syncthreads();
  if (tid < 64) {
    float acc = b5[tid];
#pragma unroll 4
    for (int k = 0; k < 128; ++k) acc = fmaf(r2_s[k], W5[k * 64 + tid], acc);
    out[b * 64 + tid] = acc;
  }
}

extern "C" void kernel_launch(void* const* d_in, const int* in_sizes, int n_in,
                              void* d_out, int out_size, void* d_ws, size_t ws_size,
                              hipStream_t stream) {
  const float* dm      = (const float*)d_in[0];
  const int*   lengths = (const int*)d_in[1];
  const float* W1 = (const float*)d_in[2];
  const float* b1 = (const float*)d_in[3];
  const float* W2 = (const float*)d_in[4];
  const float* b2 = (const float*)d_in[5];
  const float* W3 = (const float*)d_in[6];
  const float* b3 = (const float*)d_in[7];
  const float* W4 = (const float*)d_in[8];
  const float* b4 = (const float*)d_in[9];
  const float* W5 = (const float*)d_in[10];
  const float* b5 = (const float*)d_in[11];

  float* ws = (float*)d_ws;
  float* alpha_g = ws;                 // 128*65 = 8320
  float* beta_g  = ws + 8320;          // 8320
  float* tsort   = ws + 16640;         // 64
  float* pooled  = ws + 16704;         // 32*128 = 4096

  build_tables<<<SEGS, 128, 0, stream>>>(W1, b1, W2, b2, alpha_g, beta_g, tsort, pooled);
  phi_pool<<<dim3(32, 2, NB), 256, 0, stream>>>(dm, lengths, alpha_g, beta_g, tsort, pooled);
  rho_mlp<<<NB, 256, 0, stream>>>(pooled, W3, b3, W4, b4, W5, b5, (float*)d_out);
}

// Round 2
// 158.920 us; speedup vs baseline: 1.1564x; 1.1564x over previous
//
#include <hip/hip_runtime.h>
#include <hip/hip_bf16.h>

// ScalarDistanceDeepSet: B=32, N=256, pairs P=32640 (upper tri, k=1)
// phi: s -> relu(s*W1+b1)[64] -> relu(.@W2+b2)[128], masked sum over pairs
// rho: pooled[128] -> 256 -> 128 -> 64
//
// g_e(s) is piecewise-linear in s with 64 shared breakpoints. Tables
// alpha/beta[seg][e] make per-(pair,channel) work 1 FMA + 1 max. EXACT.
//
// R2: wave-per-pair (s wave-uniform via v_readlane), channel-per-lane,
// seg-major float2 table -> contiguous conflict-free ds_read_b64;
// segment via ballot(t_lane < s) + popcount instead of LDS binary search.

#define NB 32
#define NN 256
#define PHI2 128
#define SEGS 65

// ---------------- Kernel A: build tables ----------------
// grid: 65 blocks (one per segment), 128 threads (one per output channel e)
__global__ __launch_bounds__(128) void build_tables(
    const float* __restrict__ W1, const float* __restrict__ b1,
    const float* __restrict__ W2, const float* __restrict__ b2,
    float2* __restrict__ table2,   // [2][SEGS][64] {alpha,beta}
    float* __restrict__ tsort, float* __restrict__ pooled) {
  __shared__ float t_s[64], w1_s[64], b1_s[64];
  __shared__ int cat_s[64], rank_s[64];
  const int tid = threadIdx.x;
  const int seg = blockIdx.x;
  if (tid < 64) {
    float w = W1[tid], bb = b1[tid];
    w1_s[tid] = w; b1_s[tid] = bb;
    int cat; float t;
    if (w > 0.f)      { cat = 0; t = -bb / w; }   // active for s > t
    else if (w < 0.f) { cat = 1; t = -bb / w; }   // active for s < t
    else              { cat = (bb > 0.f) ? 2 : 3; t = 0.f; } // always/never
    t_s[tid] = t; cat_s[tid] = cat;
  }
  __syncthreads();
  if (tid < 64) {
    float t = t_s[tid]; int r = 0;
    for (int k = 0; k < 64; ++k) {
      float tk = t_s[k];
      r += (tk < t) || (tk == t && k < tid);   // stable rank
    }
    rank_s[tid] = r;
    if (seg == 0) tsort[r] = t;
  }
  __syncthreads();
  // channel e = tid. seg(s) = #breakpoints strictly < s.
  // cat0 (w>0): active iff seg > rank ; cat1 (w<0): active iff seg <= rank.
  float a = 0.f, bsum = b2[tid];
  for (int j = 0; j < 64; ++j) {
    int cat = cat_s[j], r = rank_s[j];
    bool act = (cat == 0) ? (seg > r) : (cat == 1) ? (seg <= r) : (cat == 2);
    float w2 = W2[j * PHI2 + tid];
    float m = act ? 1.f : 0.f;
    a    = fmaf(m * w1_s[j], w2, a);
    bsum = fmaf(m * b1_s[j], w2, bsum);
  }
  const int h = tid >> 6, l = tid & 63;
  table2[((h * SEGS) + seg) * 64 + l] = make_float2(a, bsum);
  if (seg == 0) {
    for (int i = tid; i < NB * PHI2; i += 128) pooled[i] = 0.f;
  }
}

// ---------------- Kernel B: phi + masked pooling ----------------
// grid: (32 row-chunks, 2 e-halves, 32 batches) x 256 threads (4 waves).
// Wave w of block chunk owns rows i0 = chunk*4 + w + 128*t. Lanes load 64
// consecutive row elements coalesced; inner loop broadcasts s (readlane),
// computes pos = popc(ballot(t < s)), then each lane does its channel:
// one contiguous ds_read_b64 + fma + max + add.
__global__ __launch_bounds__(256) void phi_pool(
    const float* __restrict__ dm, const int* __restrict__ lengths,
    const float2* __restrict__ table2, const float* __restrict__ tsort,
    float* __restrict__ pooled) {
  __shared__ float2 ab_s[SEGS * 64];   // 33,280 B
  __shared__ float red_s[4][64];
  const int chunk = blockIdx.x;   // 0..31
  const int h     = blockIdx.y;   // e-half
  const int b     = blockIdx.z;   // batch
  const int tid = threadIdx.x;
  const int lane = tid & 63, w = tid >> 6;

  const float2* tg = table2 + h * SEGS * 64;
  for (int i = tid; i < SEGS * 64; i += 256) ab_s[i] = tg[i];
  __syncthreads();

  const float tv = tsort[lane];      // breakpoint in register, one per lane
  const int len = lengths[b];
  const float* dmb = dm + (size_t)b * (NN * NN);
  float acc = 0.f;

  for (int i0 = chunk * 4 + w; i0 < len - 1; i0 += 128) {
    const float* row = dmb + i0 * NN + i0 + 1;
    const int cnt_total = len - 1 - i0;
    for (int base = 0; base < cnt_total; base += 64) {
      const int cnt = min(64, cnt_total - base);
      float sv = (lane < cnt) ? row[base + lane] : 0.f;
      if (cnt == 64) {
#pragma unroll 8
        for (int j = 0; j < 64; ++j) {
          float s = __int_as_float(__builtin_amdgcn_readlane(__float_as_int(sv), j));
          int pos = (int)__popcll(__ballot(tv < s));
          float2 ab = ab_s[pos * 64 + lane];
          acc += fmaxf(fmaf(ab.x, s, ab.y), 0.f);
        }
      } else {
        for (int j = 0; j < cnt; ++j) {
          float s = __int_as_float(__builtin_amdgcn_readlane(__float_as_int(sv), j));
          int pos = (int)__popcll(__ballot(tv < s));
          float2 ab = ab_s[pos * 64 + lane];
          acc += fmaxf(fmaf(ab.x, s, ab.y), 0.f);
        }
      }
    }
  }
  red_s[w][lane] = acc;
  __syncthreads();
  if (w == 0) {
    float v = red_s[0][lane] + red_s[1][lane] + red_s[2][lane] + red_s[3][lane];
    atomicAdd(&pooled[b * PHI2 + h * 64 + lane], v);
  }
}

// ---------------- Kernel C: rho MLP ----------------
__global__ __launch_bounds__(256) void rho_mlp(
    const float* __restrict__ pooled,
    const float* __restrict__ W3, const float* __restrict__ b3,
    const float* __restrict__ W4, const float* __restrict__ b4,
    const float* __restrict__ W5, const float* __restrict__ b5,
    float* __restrict__ out) {
  __shared__ float p_s[128], r1_s[256], r2_s[128];
  const int b = blockIdx.x, tid = threadIdx.x;
  if (tid < 128) p_s[tid] = pooled[b * 128 + tid];
  __syncthreads();
  {
    float acc = b3[tid];
#pragma unroll 4
    for (int k = 0; k < 128; ++k) acc = fmaf(p_s[k], W3[k * 256 + tid], acc);
    r1_s[tid] = fmaxf(acc, 0.f);
  }
  __syncthreads();
  if (tid < 128) {
    float acc = b4[tid];
#pragma unroll 4
    for (int k = 0; k < 256; ++k) acc = fmaf(r1_s[k], W4[k * 128 + tid], acc);
    r2_s[tid] = fmaxf(acc, 0.f);
  }
  __syncthreads();
  if (tid < 64) {
    float acc = b5[tid];
#pragma unroll 4
    for (int k = 0; k < 128; ++k) acc = fmaf(r2_s[k], W5[k * 64 + tid], acc);
    out[b * 64 + tid] = acc;
  }
}

extern "C" void kernel_launch(void* const* d_in, const int* in_sizes, int n_in,
                              void* d_out, int out_size, void* d_ws, size_t ws_size,
                              hipStream_t stream) {
  const float* dm      = (const float*)d_in[0];
  const int*   lengths = (const int*)d_in[1];
  const float* W1 = (const float*)d_in[2];
  const float* b1 = (const float*)d_in[3];
  const float* W2 = (const float*)d_in[4];
  const float* b2 = (const float*)d_in[5];
  const float* W3 = (const float*)d_in[6];
  const float* b3 = (const float*)d_in[7];
  const float* W4 = (const float*)d_in[8];
  const float* b4 = (const float*)d_in[9];
  const float* W5 = (const float*)d_in[10];
  const float* b5 = (const float*)d_in[11];

  float* ws = (float*)d_ws;
  float2* table2 = (float2*)ws;          // 2*65*64 float2 = 16640 floats
  float* tsort   = ws + 16640;           // 64
  float* pooled  = ws + 16704;           // 32*128 = 4096

  build_tables<<<SEGS, 128, 0, stream>>>(W1, b1, W2, b2, table2, tsort, pooled);
  phi_pool<<<dim3(32, 2, NB), 256, 0, stream>>>(dm, lengths, table2, tsort, pooled);
  rho_mlp<<<NB, 256, 0, stream>>>(pooled, W3, b3, W4, b4, W5, b5, (float*)d_out);
}

// Round 3
// 157.401 us; speedup vs baseline: 1.1676x; 1.0096x over previous
//
#include <hip/hip_runtime.h>
#include <hip/hip_bf16.h>

// ScalarDistanceDeepSet: B=32, N=256, pairs P=32640 (upper tri, k=1)
// phi: s -> relu(s*W1+b1)[64] -> relu(.@W2+b2)[128], masked sum over pairs
// rho: pooled[128] -> 256 -> 128 -> 64
//
// g_e(s) is piecewise-linear in s with 64 shared breakpoints. Tables
// alpha/beta[seg][e] make per-(pair,channel) work 1 FMA + 1 max. EXACT.
//
// R3: (a) rho_mlp stages W3/W4/W5 through a reused 128KB LDS buffer with
// independent float4 loads (was: serial dependent global-load FMA chain,
// 48us latency-bound at 1% occupancy). (b) build_tables stages W2 in LDS.
// (c) phi_pool handles BOTH e-halves per block (table 65KB in LDS): each
// pair broadcast once for all 128 channels; early-exit for workless blocks.

#define NB 32
#define NN 256
#define PHI2 128
#define SEGS 65

// ---------------- Kernel A: build tables ----------------
// grid: 65 blocks (one per segment), 128 threads (one per output channel e)
__global__ __launch_bounds__(128) void build_tables(
    const float* __restrict__ W1, const float* __restrict__ b1,
    const float* __restrict__ W2, const float* __restrict__ b2,
    float2* __restrict__ table2,   // [SEGS][128] {alpha,beta}
    float* __restrict__ tsort, float* __restrict__ pooled) {
  __shared__ float w2_s[64 * PHI2];   // 32 KB
  __shared__ float t_s[64], w1_s[64], b1_s[64];
  __shared__ int cat_s[64], rank_s[64];
  const int tid = threadIdx.x;
  const int seg = blockIdx.x;
  // stage W2 with independent vector loads
  const float4* W2v = (const float4*)W2;
  float4* w2v = (float4*)w2_s;
  for (int i = tid; i < 64 * PHI2 / 4; i += 128) w2v[i] = W2v[i];
  if (tid < 64) {
    float w = W1[tid], bb = b1[tid];
    w1_s[tid] = w; b1_s[tid] = bb;
    int cat; float t;
    if (w > 0.f)      { cat = 0; t = -bb / w; }   // active for s > t
    else if (w < 0.f) { cat = 1; t = -bb / w; }   // active for s < t
    else              { cat = (bb > 0.f) ? 2 : 3; t = 0.f; } // always/never
    t_s[tid] = t; cat_s[tid] = cat;
  }
  __syncthreads();
  if (tid < 64) {
    float t = t_s[tid]; int r = 0;
    for (int k = 0; k < 64; ++k) {
      float tk = t_s[k];
      r += (tk < t) || (tk == t && k < tid);   // stable rank
    }
    rank_s[tid] = r;
    if (seg == 0) tsort[r] = t;
  }
  __syncthreads();
  // channel e = tid. seg(s) = #breakpoints strictly < s.
  // cat0 (w>0): active iff seg > rank ; cat1 (w<0): active iff seg <= rank.
  float a = 0.f, bsum = b2[tid];
#pragma unroll 8
  for (int j = 0; j < 64; ++j) {
    int cat = cat_s[j], r = rank_s[j];
    bool act = (cat == 0) ? (seg > r) : (cat == 1) ? (seg <= r) : (cat == 2);
    float w2 = w2_s[j * PHI2 + tid];
    float m = act ? 1.f : 0.f;
    a    = fmaf(m * w1_s[j], w2, a);
    bsum = fmaf(m * b1_s[j], w2, bsum);
  }
  table2[seg * PHI2 + tid] = make_float2(a, bsum);
  if (seg == 0) {
    for (int i = tid; i < NB * PHI2; i += 128) pooled[i] = 0.f;
  }
}

// ---------------- Kernel B: phi + masked pooling ----------------
// grid: (32 row-chunks, 32 batches) x 256 threads (4 waves).
// Wave w owns rows i0 = chunk*4 + w + 128*t. Lanes load 64 consecutive row
// elements coalesced; inner loop broadcasts s (readlane), computes
// pos = popc(ballot(t < s)) from register-held breakpoints, then each lane
// evaluates channels (lane, lane+64): 2 contiguous ds_read_b64 + fma/max.
__global__ __launch_bounds__(256) void phi_pool(
    const float* __restrict__ dm, const int* __restrict__ lengths,
    const float2* __restrict__ table2, const float* __restrict__ tsort,
    float* __restrict__ pooled) {
  __shared__ float2 ab_s[SEGS * PHI2];   // 66,560 B
  __shared__ float red_s[4][PHI2];
  const int chunk = blockIdx.x;   // 0..31
  const int b     = blockIdx.y;   // batch
  const int tid = threadIdx.x;
  const int lane = tid & 63, w = tid >> 6;

  const int len = lengths[b];
  if (chunk * 4 >= len - 1) return;   // block-uniform: no rows for this block

  for (int i = tid; i < SEGS * PHI2; i += 256) ab_s[i] = table2[i];
  __syncthreads();

  const float tv = tsort[lane];      // breakpoint in register, one per lane
  const float* dmb = dm + (size_t)b * (NN * NN);
  float acc0 = 0.f, acc1 = 0.f;

  for (int i0 = chunk * 4 + w; i0 < len - 1; i0 += 128) {
    const float* row = dmb + i0 * NN + i0 + 1;
    const int cnt_total = len - 1 - i0;
    for (int base = 0; base < cnt_total; base += 64) {
      const int cnt = min(64, cnt_total - base);
      float sv = (lane < cnt) ? row[base + lane] : 0.f;
      if (cnt == 64) {
#pragma unroll 8
        for (int j = 0; j < 64; ++j) {
          float s = __int_as_float(__builtin_amdgcn_readlane(__float_as_int(sv), j));
          int pos = (int)__popcll(__ballot(tv < s));
          const float2* rowp = ab_s + pos * PHI2;
          float2 p0 = rowp[lane];
          float2 p1 = rowp[64 + lane];
          acc0 += fmaxf(fmaf(p0.x, s, p0.y), 0.f);
          acc1 += fmaxf(fmaf(p1.x, s, p1.y), 0.f);
        }
      } else {
        for (int j = 0; j < cnt; ++j) {
          float s = __int_as_float(__builtin_amdgcn_readlane(__float_as_int(sv), j));
          int pos = (int)__popcll(__ballot(tv < s));
          const float2* rowp = ab_s + pos * PHI2;
          float2 p0 = rowp[lane];
          float2 p1 = rowp[64 + lane];
          acc0 += fmaxf(fmaf(p0.x, s, p0.y), 0.f);
          acc1 += fmaxf(fmaf(p1.x, s, p1.y), 0.f);
        }
      }
    }
  }
  red_s[w][lane] = acc0;
  red_s[w][64 + lane] = acc1;
  __syncthreads();
  if (tid < PHI2) {
    float v = red_s[0][tid] + red_s[1][tid] + red_s[2][tid] + red_s[3][tid];
    atomicAdd(&pooled[b * PHI2 + tid], v);
  }
}

// ---------------- Kernel C: rho MLP ----------------
// grid: 32 blocks (one per batch), 256 threads. All weight layers staged
// through one reused 128 KB LDS buffer with independent float4 loads.
__global__ __launch_bounds__(256) void rho_mlp(
    const float* __restrict__ pooled,
    const float* __restrict__ W3, const float* __restrict__ b3,
    const float* __restrict__ W4, const float* __restrict__ b4,
    const float* __restrict__ W5, const float* __restrict__ b5,
    float* __restrict__ out) {
  __shared__ float w_s[128 * 256];     // 128 KB, reused per layer
  __shared__ float p_s[128], r1_s[256], r2_s[128];
  const int b = blockIdx.x, tid = threadIdx.x;
  float4* wsv = (float4*)w_s;
  // stage W3 (128x256 = 32768 floats = 8192 float4)
  {
    const float4* w3v = (const float4*)W3;
    for (int i = tid; i < 8192; i += 256) wsv[i] = w3v[i];
  }
  if (tid < 128) p_s[tid] = pooled[b * 128 + tid];
  __syncthreads();
  {
    float acc = b3[tid];
#pragma unroll 8
    for (int k = 0; k < 128; ++k) acc = fmaf(p_s[k], w_s[k * 256 + tid], acc);
    r1_s[tid] = fmaxf(acc, 0.f);
  }
  __syncthreads();
  // stage W4 (256x128 = 32768 floats)
  {
    const float4* w4v = (const float4*)W4;
    for (int i = tid; i < 8192; i += 256) wsv[i] = w4v[i];
  }
  __syncthreads();
  if (tid < 128) {
    float acc = b4[tid];
#pragma unroll 8
    for (int k = 0; k < 256; ++k) acc = fmaf(r1_s[k], w_s[k * 128 + tid], acc);
    r2_s[tid] = fmaxf(acc, 0.f);
  }
  __syncthreads();
  // stage W5 (128x64 = 8192 floats = 2048 float4)
  {
    const float4* w5v = (const float4*)W5;
    for (int i = tid; i < 2048; i += 256) wsv[i] = w5v[i];
  }
  __syncthreads();
  if (tid < 64) {
    float acc = b5[tid];
#pragma unroll 8
    for (int k = 0; k < 128; ++k) acc = fmaf(r2_s[k], w_s[k * 64 + tid], acc);
    out[b * 64 + tid] = acc;
  }
}

extern "C" void kernel_launch(void* const* d_in, const int* in_sizes, int n_in,
                              void* d_out, int out_size, void* d_ws, size_t ws_size,
                              hipStream_t stream) {
  const float* dm      = (const float*)d_in[0];
  const int*   lengths = (const int*)d_in[1];
  const float* W1 = (const float*)d_in[2];
  const float* b1 = (const float*)d_in[3];
  const float* W2 = (const float*)d_in[4];
  const float* b2 = (const float*)d_in[5];
  const float* W3 = (const float*)d_in[6];
  const float* b3 = (const float*)d_in[7];
  const float* W4 = (const float*)d_in[8];
  const float* b4 = (const float*)d_in[9];
  const float* W5 = (const float*)d_in[10];
  const float* b5 = (const float*)d_in[11];

  float* ws = (float*)d_ws;
  float2* table2 = (float2*)ws;          // 65*128 float2 = 16640 floats
  float* tsort   = ws + 16640;           // 64
  float* pooled  = ws + 16704;           // 32*128 = 4096

  build_tables<<<SEGS, 128, 0, stream>>>(W1, b1, W2, b2, table2, tsort, pooled);
  phi_pool<<<dim3(32, NB), 256, 0, stream>>>(dm, lengths, table2, tsort, pooled);
  rho_mlp<<<NB, 256, 0, stream>>>(pooled, W3, b3, W4, b4, W5, b5, (float*)d_out);
}

// Round 4
// 142.932 us; speedup vs baseline: 1.2858x; 1.1012x over previous
//
#include <hip/hip_runtime.h>
#include <hip/hip_bf16.h>

// ScalarDistanceDeepSet: B=32, N=256, pairs P=32640 (upper tri, k=1)
// phi: s -> relu(s*W1+b1)[64] -> relu(.@W2+b2)[128], masked sum over pairs
// rho: pooled[128] -> 256 -> 128 -> 64
//
// g_e(s) is piecewise-linear in s with 64 shared breakpoints. Tables
// alpha/beta[seg][e] make per-(pair,channel) work 1 FMA + 1 max. EXACT.
//
// R4: phi_pool was 90% stalled (VALUBusy 9.5%, 2 waves/SIMD). Changes:
// 512-thread blocks (4 waves/SIMD at same 66.5KB LDS), software prefetch of
// the next row chunk across the 64-pair burst, float4-packed table (one
// ds_read_b128 per pair), direct per-wave atomics (no final barrier).

#define NB 32
#define NN 256
#define PHI2 128
#define SEGS 65

// ---------------- Kernel A: build tables ----------------
// grid: 65 blocks (one per segment), 128 threads (one per output channel e)
// table4[seg][l] = {alpha[l], beta[l], alpha[l+64], beta[l+64]}
__global__ __launch_bounds__(128) void build_tables(
    const float* __restrict__ W1, const float* __restrict__ b1,
    const float* __restrict__ W2, const float* __restrict__ b2,
    float4* __restrict__ table4,   // [SEGS][64]
    float* __restrict__ tsort, float* __restrict__ pooled) {
  __shared__ float w2_s[64 * PHI2];   // 32 KB
  __shared__ float t_s[64], w1_s[64], b1_s[64];
  __shared__ float a_sh[128], b_sh[128];
  __shared__ int cat_s[64], rank_s[64];
  const int tid = threadIdx.x;
  const int seg = blockIdx.x;
  const float4* W2v = (const float4*)W2;
  float4* w2v = (float4*)w2_s;
  for (int i = tid; i < 64 * PHI2 / 4; i += 128) w2v[i] = W2v[i];
  if (tid < 64) {
    float w = W1[tid], bb = b1[tid];
    w1_s[tid] = w; b1_s[tid] = bb;
    int cat; float t;
    if (w > 0.f)      { cat = 0; t = -bb / w; }   // active for s > t
    else if (w < 0.f) { cat = 1; t = -bb / w; }   // active for s < t
    else              { cat = (bb > 0.f) ? 2 : 3; t = 0.f; } // always/never
    t_s[tid] = t; cat_s[tid] = cat;
  }
  __syncthreads();
  if (tid < 64) {
    float t = t_s[tid]; int r = 0;
    for (int k = 0; k < 64; ++k) {
      float tk = t_s[k];
      r += (tk < t) || (tk == t && k < tid);   // stable rank
    }
    rank_s[tid] = r;
    if (seg == 0) tsort[r] = t;
  }
  __syncthreads();
  // channel e = tid. seg(s) = #breakpoints strictly < s.
  float a = 0.f, bsum = b2[tid];
#pragma unroll 8
  for (int j = 0; j < 64; ++j) {
    int cat = cat_s[j], r = rank_s[j];
    bool act = (cat == 0) ? (seg > r) : (cat == 1) ? (seg <= r) : (cat == 2);
    float w2 = w2_s[j * PHI2 + tid];
    float m = act ? 1.f : 0.f;
    a    = fmaf(m * w1_s[j], w2, a);
    bsum = fmaf(m * b1_s[j], w2, bsum);
  }
  a_sh[tid] = a; b_sh[tid] = bsum;
  __syncthreads();
  if (tid < 64)
    table4[seg * 64 + tid] =
        make_float4(a_sh[tid], b_sh[tid], a_sh[tid + 64], b_sh[tid + 64]);
  if (seg == 0) {
    for (int i = tid; i < NB * PHI2; i += 128) pooled[i] = 0.f;
  }
}

// ---------------- Kernel B: phi + masked pooling ----------------
// grid: (16 row-chunks, 32 batches) x 512 threads (8 waves).
// Wave w owns rows i0 = chunk*8 + w + 128*t. Lanes load 64 consecutive row
// elements coalesced (next chunk prefetched across the burst); inner loop
// broadcasts s (readlane), pos = popc(ballot(t < s)) from register-held
// breakpoints; each lane evaluates channels (lane, lane+64) via one
// contiguous ds_read_b128. Per-wave atomics, no final barrier.
__global__ __launch_bounds__(512) void phi_pool(
    const float* __restrict__ dm, const int* __restrict__ lengths,
    const float4* __restrict__ table4, const float* __restrict__ tsort,
    float* __restrict__ pooled) {
  __shared__ float4 ab_s[SEGS * 64];   // 66,560 B
  const int chunk = blockIdx.x;   // 0..15
  const int b     = blockIdx.y;   // batch
  const int tid = threadIdx.x;
  const int lane = tid & 63, w = tid >> 6;

  const int len = lengths[b];
  if (chunk * 8 >= len - 1) return;   // block-uniform: no rows for this block

  for (int i = tid; i < SEGS * 64; i += 512) ab_s[i] = table4[i];
  __syncthreads();

  const float tv = tsort[lane];      // breakpoint in register, one per lane
  const float* dmb = dm + (size_t)b * (NN * NN);
  float acc0 = 0.f, acc1 = 0.f;

  for (int i0 = chunk * 8 + w; i0 < len - 1; i0 += 128) {
    const float* row = dmb + i0 * NN + i0 + 1;
    const int cnt_total = len - 1 - i0;
    float sv = (lane < cnt_total) ? row[lane] : 0.f;
    for (int base = 0; base < cnt_total; base += 64) {
      const int cnt = min(64, cnt_total - base);
      // prefetch next chunk while this burst computes
      const int nb = base + 64;
      float svn = 0.f;
      if (nb < cnt_total && lane < cnt_total - nb) svn = row[nb + lane];
      if (cnt == 64) {
#pragma unroll 8
        for (int j = 0; j < 64; ++j) {
          float s = __int_as_float(__builtin_amdgcn_readlane(__float_as_int(sv), j));
          int pos = (int)__popcll(__ballot(tv < s));
          float4 p = ab_s[pos * 64 + lane];
          acc0 += fmaxf(fmaf(p.x, s, p.y), 0.f);
          acc1 += fmaxf(fmaf(p.z, s, p.w), 0.f);
        }
      } else {
        for (int j = 0; j < cnt; ++j) {
          float s = __int_as_float(__builtin_amdgcn_readlane(__float_as_int(sv), j));
          int pos = (int)__popcll(__ballot(tv < s));
          float4 p = ab_s[pos * 64 + lane];
          acc0 += fmaxf(fmaf(p.x, s, p.y), 0.f);
          acc1 += fmaxf(fmaf(p.z, s, p.w), 0.f);
        }
      }
      sv = svn;
    }
  }
  atomicAdd(&pooled[b * PHI2 + lane], acc0);
  atomicAdd(&pooled[b * PHI2 + 64 + lane], acc1);
}

// ---------------- Kernel C: rho MLP ----------------
// grid: 32 blocks (one per batch), 256 threads. All weight layers staged
// through one reused 128 KB LDS buffer with independent float4 loads.
__global__ __launch_bounds__(256) void rho_mlp(
    const float* __restrict__ pooled,
    const float* __restrict__ W3, const float* __restrict__ b3,
    const float* __restrict__ W4, const float* __restrict__ b4,
    const float* __restrict__ W5, const float* __restrict__ b5,
    float* __restrict__ out) {
  __shared__ float w_s[128 * 256];     // 128 KB, reused per layer
  __shared__ float p_s[128], r1_s[256], r2_s[128];
  const int b = blockIdx.x, tid = threadIdx.x;
  float4* wsv = (float4*)w_s;
  {
    const float4* w3v = (const float4*)W3;
    for (int i = tid; i < 8192; i += 256) wsv[i] = w3v[i];
  }
  if (tid < 128) p_s[tid] = pooled[b * 128 + tid];
  __syncthreads();
  {
    float acc = b3[tid];
#pragma unroll 8
    for (int k = 0; k < 128; ++k) acc = fmaf(p_s[k], w_s[k * 256 + tid], acc);
    r1_s[tid] = fmaxf(acc, 0.f);
  }
  __syncthreads();
  {
    const float4* w4v = (const float4*)W4;
    for (int i = tid; i < 8192; i += 256) wsv[i] = w4v[i];
  }
  __syncthreads();
  if (tid < 128) {
    float acc = b4[tid];
#pragma unroll 8
    for (int k = 0; k < 256; ++k) acc = fmaf(r1_s[k], w_s[k * 128 + tid], acc);
    r2_s[tid] = fmaxf(acc, 0.f);
  }
  __syncthreads();
  {
    const float4* w5v = (const float4*)W5;
    for (int i = tid; i < 2048; i += 256) wsv[i] = w5v[i];
  }
  __syncthreads();
  if (tid < 64) {
    float acc = b5[tid];
#pragma unroll 8
    for (int k = 0; k < 128; ++k) acc = fmaf(r2_s[k], w_s[k * 64 + tid], acc);
    out[b * 64 + tid] = acc;
  }
}

extern "C" void kernel_launch(void* const* d_in, const int* in_sizes, int n_in,
                              void* d_out, int out_size, void* d_ws, size_t ws_size,
                              hipStream_t stream) {
  const float* dm      = (const float*)d_in[0];
  const int*   lengths = (const int*)d_in[1];
  const float* W1 = (const float*)d_in[2];
  const float* b1 = (const float*)d_in[3];
  const float* W2 = (const float*)d_in[4];
  const float* b2 = (const float*)d_in[5];
  const float* W3 = (const float*)d_in[6];
  const float* b3 = (const float*)d_in[7];
  const float* W4 = (const float*)d_in[8];
  const float* b4 = (const float*)d_in[9];
  const float* W5 = (const float*)d_in[10];
  const float* b5 = (const float*)d_in[11];

  float* ws = (float*)d_ws;
  float4* table4 = (float4*)ws;          // 65*64 float4 = 16640 floats
  float* tsort   = ws + 16640;           // 64
  float* pooled  = ws + 16704;           // 32*128 = 4096

  build_tables<<<SEGS, 128, 0, stream>>>(W1, b1, W2, b2, table4, tsort, pooled);
  phi_pool<<<dim3(16, NB), 512, 0, stream>>>(dm, lengths, table4, tsort, pooled);
  rho_mlp<<<NB, 256, 0, stream>>>(pooled, W3, b3, W4, b4, W5, b5, (float*)d_out);
}

// Round 5
// 132.908 us; speedup vs baseline: 1.3827x; 1.0754x over previous
//
#include <hip/hip_runtime.h>
#include <hip/hip_bf16.h>

// ScalarDistanceDeepSet: B=32, N=256, pairs P=32640 (upper tri, k=1)
// phi: s -> relu(s*W1+b1)[64] -> relu(.@W2+b2)[128], masked sum over pairs
// rho: pooled[128] -> 256 -> 128 -> 64
//
// g_e(s) is piecewise-linear in s with 64 shared breakpoints. Tables
// alpha/beta[seg][e] make per-(pair,channel) work 1 FMA + 1 max. EXACT.
//
// R5: phi_pool occupancy + balance. Half-channel blocks (33.3KB float2
// table -> ds_read_b64/pair) with __launch_bounds__(512,8) -> 4 blocks/CU
// = 32 waves/CU (was 16). Mirror-row pairing (wave owns row r and 254-r)
// removes the 2.7x chunk imbalance. s/pos stay in SGPRs (readlane/ballot).

#define NB 32
#define NN 256
#define PHI2 128
#define SEGS 65

// ---------------- Kernel A: build tables ----------------
// grid: 65 blocks (one per segment), 128 threads (one per output channel e)
// table2[h][seg][l] = {alpha, beta} for channel h*64+l
__global__ __launch_bounds__(128) void build_tables(
    const float* __restrict__ W1, const float* __restrict__ b1,
    const float* __restrict__ W2, const float* __restrict__ b2,
    float2* __restrict__ table2,   // [2][SEGS][64]
    float* __restrict__ tsort, float* __restrict__ pooled) {
  __shared__ float w2_s[64 * PHI2];   // 32 KB
  __shared__ float t_s[64], w1_s[64], b1_s[64];
  __shared__ int cat_s[64], rank_s[64];
  const int tid = threadIdx.x;
  const int seg = blockIdx.x;
  const float4* W2v = (const float4*)W2;
  float4* w2v = (float4*)w2_s;
  for (int i = tid; i < 64 * PHI2 / 4; i += 128) w2v[i] = W2v[i];
  if (tid < 64) {
    float w = W1[tid], bb = b1[tid];
    w1_s[tid] = w; b1_s[tid] = bb;
    int cat; float t;
    if (w > 0.f)      { cat = 0; t = -bb / w; }   // active for s > t
    else if (w < 0.f) { cat = 1; t = -bb / w; }   // active for s < t
    else              { cat = (bb > 0.f) ? 2 : 3; t = 0.f; } // always/never
    t_s[tid] = t; cat_s[tid] = cat;
  }
  __syncthreads();
  if (tid < 64) {
    float t = t_s[tid]; int r = 0;
    for (int k = 0; k < 64; ++k) {
      float tk = t_s[k];
      r += (tk < t) || (tk == t && k < tid);   // stable rank
    }
    rank_s[tid] = r;
    if (seg == 0) tsort[r] = t;
  }
  __syncthreads();
  // channel e = tid. seg(s) = #breakpoints strictly < s.
  float a = 0.f, bsum = b2[tid];
#pragma unroll 8
  for (int j = 0; j < 64; ++j) {
    int cat = cat_s[j], r = rank_s[j];
    bool act = (cat == 0) ? (seg > r) : (cat == 1) ? (seg <= r) : (cat == 2);
    float w2 = w2_s[j * PHI2 + tid];
    float m = act ? 1.f : 0.f;
    a    = fmaf(m * w1_s[j], w2, a);
    bsum = fmaf(m * b1_s[j], w2, bsum);
  }
  const int h = tid >> 6, l = tid & 63;
  table2[((h * SEGS) + seg) * 64 + l] = make_float2(a, bsum);
  if (seg == 0) {
    for (int i = tid; i < NB * PHI2; i += 128) pooled[i] = 0.f;
  }
}

// ---------------- Kernel B: phi + masked pooling ----------------
// grid: (16 row-chunks, 2 halves, 32 batches) x 512 threads (8 waves).
// Wave w owns row r = chunk*8+w (0..127) AND its mirror 254-r -> per-wave
// pair count is uniform (256 for full-length batches). Lanes load 64
// consecutive row elements coalesced (next chunk prefetched); inner loop
// broadcasts s (readlane -> SGPR), pos = popc(ballot(t < s)); each lane
// evaluates its channel via one contiguous ds_read_b64. Per-wave atomics.
__global__ __launch_bounds__(512, 8) void phi_pool(
    const float* __restrict__ dm, const int* __restrict__ lengths,
    const float2* __restrict__ table2, const float* __restrict__ tsort,
    float* __restrict__ pooled) {
  __shared__ float2 ab_s[SEGS * 64];   // 33,280 B -> 4 blocks/CU
  const int chunk = blockIdx.x;   // 0..15
  const int h     = blockIdx.y;   // channel half
  const int b     = blockIdx.z;   // batch
  const int tid = threadIdx.x;
  const int lane = tid & 63, w = tid >> 6;

  const int len = lengths[b];
  // block-uniform early exit: no primary row (8c) and no mirror row (247-8c)
  if (8 * chunk > len - 2 && 247 - 8 * chunk > len - 2) return;

  const float2* tg = table2 + h * SEGS * 64;
  for (int i = tid; i < SEGS * 64; i += 512) ab_s[i] = tg[i];
  __syncthreads();

  const float tv = tsort[lane];      // breakpoint in register, one per lane
  const float* dmb = dm + (size_t)b * (NN * NN);
  float acc = 0.f;

  const int r1 = chunk * 8 + w;      // 0..127
#pragma unroll
  for (int t = 0; t < 2; ++t) {
    const int i0 = (t == 0) ? r1 : 254 - r1;
    if (t == 1 && i0 == r1) continue;     // r1 == 127: mirror is itself
    if (i0 > len - 2) continue;
    const float* row = dmb + i0 * NN + i0 + 1;
    const int cnt_total = len - 1 - i0;
    float sv = (lane < cnt_total) ? row[lane] : 0.f;
    for (int base = 0; base < cnt_total; base += 64) {
      const int cnt = min(64, cnt_total - base);
      // prefetch next chunk while this burst computes
      const int nb = base + 64;
      float svn = 0.f;
      if (nb < cnt_total && lane < cnt_total - nb) svn = row[nb + lane];
      if (cnt == 64) {
#pragma unroll 8
        for (int j = 0; j < 64; ++j) {
          float s = __int_as_float(__builtin_amdgcn_readlane(__float_as_int(sv), j));
          int pos = (int)__popcll(__ballot(tv < s));
          float2 p = ab_s[pos * 64 + lane];
          acc += fmaxf(fmaf(p.x, s, p.y), 0.f);
        }
      } else {
        for (int j = 0; j < cnt; ++j) {
          float s = __int_as_float(__builtin_amdgcn_readlane(__float_as_int(sv), j));
          int pos = (int)__popcll(__ballot(tv < s));
          float2 p = ab_s[pos * 64 + lane];
          acc += fmaxf(fmaf(p.x, s, p.y), 0.f);
        }
      }
      sv = svn;
    }
  }
  atomicAdd(&pooled[b * PHI2 + h * 64 + lane], acc);
}

// ---------------- Kernel C: rho MLP ----------------
// grid: 32 blocks (one per batch), 256 threads. Weight layers staged
// through one reused 128 KB LDS buffer with independent float4 loads.
__global__ __launch_bounds__(256) void rho_mlp(
    const float* __restrict__ pooled,
    const float* __restrict__ W3, const float* __restrict__ b3,
    const float* __restrict__ W4, const float* __restrict__ b4,
    const float* __restrict__ W5, const float* __restrict__ b5,
    float* __restrict__ out) {
  __shared__ float w_s[128 * 256];     // 128 KB, reused per layer
  __shared__ float p_s[128], r1_s[256], r2_s[128];
  const int b = blockIdx.x, tid = threadIdx.x;
  float4* wsv = (float4*)w_s;
  {
    const float4* w3v = (const float4*)W3;
    for (int i = tid; i < 8192; i += 256) wsv[i] = w3v[i];
  }
  if (tid < 128) p_s[tid] = pooled[b * 128 + tid];
  __syncthreads();
  {
    float acc = b3[tid];
#pragma unroll 8
    for (int k = 0; k < 128; ++k) acc = fmaf(p_s[k], w_s[k * 256 + tid], acc);
    r1_s[tid] = fmaxf(acc, 0.f);
  }
  __syncthreads();
  {
    const float4* w4v = (const float4*)W4;
    for (int i = tid; i < 8192; i += 256) wsv[i] = w4v[i];
  }
  __syncthreads();
  if (tid < 128) {
    float acc = b4[tid];
#pragma unroll 8
    for (int k = 0; k < 256; ++k) acc = fmaf(r1_s[k], w_s[k * 128 + tid], acc);
    r2_s[tid] = fmaxf(acc, 0.f);
  }
  __syncthreads();
  {
    const float4* w5v = (const float4*)W5;
    for (int i = tid; i < 2048; i += 256) wsv[i] = w5v[i];
  }
  __syncthreads();
  if (tid < 64) {
    float acc = b5[tid];
#pragma unroll 8
    for (int k = 0; k < 128; ++k) acc = fmaf(r2_s[k], w_s[k * 64 + tid], acc);
    out[b * 64 + tid] = acc;
  }
}

extern "C" void kernel_launch(void* const* d_in, const int* in_sizes, int n_in,
                              void* d_out, int out_size, void* d_ws, size_t ws_size,
                              hipStream_t stream) {
  const float* dm      = (const float*)d_in[0];
  const int*   lengths = (const int*)d_in[1];
  const float* W1 = (const float*)d_in[2];
  const float* b1 = (const float*)d_in[3];
  const float* W2 = (const float*)d_in[4];
  const float* b2 = (const float*)d_in[5];
  const float* W3 = (const float*)d_in[6];
  const float* b3 = (const float*)d_in[7];
  const float* W4 = (const float*)d_in[8];
  const float* b4 = (const float*)d_in[9];
  const float* W5 = (const float*)d_in[10];
  const float* b5 = (const float*)d_in[11];

  float* ws = (float*)d_ws;
  float2* table2 = (float2*)ws;          // 2*65*64 float2 = 16640 floats
  float* tsort   = ws + 16640;           // 64
  float* pooled  = ws + 16704;           // 32*128 = 4096

  build_tables<<<SEGS, 128, 0, stream>>>(W1, b1, W2, b2, table2, tsort, pooled);
  phi_pool<<<dim3(16, 2, NB), 512, 0, stream>>>(dm, lengths, table2, tsort, pooled);
  rho_mlp<<<NB, 256, 0, stream>>>(pooled, W3, b3, W4, b4, W5, b5, (float*)d_out);
}

// Round 6
// 132.393 us; speedup vs baseline: 1.3881x; 1.0039x over previous
//
#include <hip/hip_runtime.h>
#include <hip/hip_bf16.h>

// ScalarDistanceDeepSet: B=32, N=256, pairs P=32640 (upper tri, k=1)
// phi: s -> relu(s*W1+b1)[64] -> relu(.@W2+b2)[128], masked sum over pairs
// rho: pooled[128] -> 256 -> 128 -> 64
//
// g_e(s) is piecewise-linear in s with 64 shared breakpoints. Tables
// alpha/beta[seg][e] make per-(pair,channel) work 1 FMA + 1 max. EXACT.
//
// R6: phi_pool row handling. Each dm row is 1KB aligned -> ONE
// global_load_dwordx4 per lane covers the whole row (256 floats/wave).
// Both primary and mirror rows issued up-front (latency overlap). Interior
// 4-element groups unguarded (uniform-SGPR readlane, static component);
// <=6 ragged edge elements per row via a small dynamic loop. Keeps R5's
// half-table (33.3KB), 512thr/(512,8) -> 32 waves/CU, ballot segment find.

#define NB 32
#define NN 256
#define PHI2 128
#define SEGS 65

// ---------------- Kernel A: build tables ----------------
// grid: 65 blocks (one per segment), 128 threads (one per output channel e)
// table2[h][seg][l] = {alpha, beta} for channel h*64+l
__global__ __launch_bounds__(128) void build_tables(
    const float* __restrict__ W1, const float* __restrict__ b1,
    const float* __restrict__ W2, const float* __restrict__ b2,
    float2* __restrict__ table2,   // [2][SEGS][64]
    float* __restrict__ tsort, float* __restrict__ pooled) {
  __shared__ float w2_s[64 * PHI2];   // 32 KB
  __shared__ float t_s[64], w1_s[64], b1_s[64];
  __shared__ int cat_s[64], rank_s[64];
  const int tid = threadIdx.x;
  const int seg = blockIdx.x;
  const float4* W2v = (const float4*)W2;
  float4* w2v = (float4*)w2_s;
  for (int i = tid; i < 64 * PHI2 / 4; i += 128) w2v[i] = W2v[i];
  if (tid < 64) {
    float w = W1[tid], bb = b1[tid];
    w1_s[tid] = w; b1_s[tid] = bb;
    int cat; float t;
    if (w > 0.f)      { cat = 0; t = -bb / w; }   // active for s > t
    else if (w < 0.f) { cat = 1; t = -bb / w; }   // active for s < t
    else              { cat = (bb > 0.f) ? 2 : 3; t = 0.f; } // always/never
    t_s[tid] = t; cat_s[tid] = cat;
  }
  __syncthreads();
  if (tid < 64) {
    float t = t_s[tid]; int r = 0;
    for (int k = 0; k < 64; ++k) {
      float tk = t_s[k];
      r += (tk < t) || (tk == t && k < tid);   // stable rank
    }
    rank_s[tid] = r;
    if (seg == 0) tsort[r] = t;
  }
  __syncthreads();
  // channel e = tid. seg(s) = #breakpoints strictly < s.
  float a = 0.f, bsum = b2[tid];
#pragma unroll 8
  for (int j = 0; j < 64; ++j) {
    int cat = cat_s[j], r = rank_s[j];
    bool act = (cat == 0) ? (seg > r) : (cat == 1) ? (seg <= r) : (cat == 2);
    float w2 = w2_s[j * PHI2 + tid];
    float m = act ? 1.f : 0.f;
    a    = fmaf(m * w1_s[j], w2, a);
    bsum = fmaf(m * b1_s[j], w2, bsum);
  }
  const int h = tid >> 6, l = tid & 63;
  table2[((h * SEGS) + seg) * 64 + l] = make_float2(a, bsum);
  if (seg == 0) {
    for (int i = tid; i < NB * PHI2; i += 128) pooled[i] = 0.f;
  }
}

// One (pair, channel) visit: broadcast s from lane L (uniform), segment via
// ballot over register-held sorted breakpoints, one contiguous ds_read_b64.
__device__ __forceinline__ void visit(float comp, int L, float tv, int lane,
                                      const float2* ab_s, float& acc) {
  float s = __int_as_float(__builtin_amdgcn_readlane(__float_as_int(comp), L));
  int pos = (int)__popcll(__ballot(tv < s));
  float2 p = ab_s[pos * 64 + lane];
  acc += fmaxf(fmaf(p.x, s, p.y), 0.f);
}

// Dynamic-component visit for ragged row edges (<=6 per row).
__device__ __forceinline__ void visit_dyn(const float4& f4, int j, float tv,
                                          int lane, const float2* ab_s,
                                          float& acc) {
  int c = j & 3;
  float comp = (c == 0) ? f4.x : (c == 1) ? f4.y : (c == 2) ? f4.z : f4.w;
  visit(comp, j >> 2, tv, lane, ab_s, acc);
}

// Process one row: f4 holds the full 256-float row across the wave
// (lane holds cols 4*lane..4*lane+3). Valid cols j in [i0+1, len-1].
__device__ __forceinline__ void do_row(const float4& f4, int i0, int len,
                                       float tv, int lane,
                                       const float2* ab_s, float& acc) {
  const int jlo = i0 + 1, jhi = len - 1;   // inclusive; jhi >= jlo guaranteed
  const int fullLo = (jlo + 3) >> 2;       // first fully-valid 4-group
  const int fullHi = (jhi >= 3) ? ((jhi - 3) >> 2) : -1;  // last fully-valid
  if (fullLo > fullHi) {
    for (int j = jlo; j <= jhi; ++j) visit_dyn(f4, j, tv, lane, ab_s, acc);
    return;
  }
  // low ragged edge
  for (int j = jlo; j < fullLo * 4; ++j) visit_dyn(f4, j, tv, lane, ab_s, acc);
  // interior full groups: uniform L in SGPR, static components
#pragma unroll 4
  for (int L = fullLo; L <= fullHi; ++L) {
    visit(f4.x, L, tv, lane, ab_s, acc);
    visit(f4.y, L, tv, lane, ab_s, acc);
    visit(f4.z, L, tv, lane, ab_s, acc);
    visit(f4.w, L, tv, lane, ab_s, acc);
  }
  // high ragged edge
  for (int j = fullHi * 4 + 4; j <= jhi; ++j)
    visit_dyn(f4, j, tv, lane, ab_s, acc);
}

// ---------------- Kernel B: phi + masked pooling ----------------
// grid: (16 row-chunks, 2 halves, 32 batches) x 512 threads (8 waves).
// Wave w owns row r = chunk*8+w (0..127) and its mirror 254-r (balanced).
__global__ __launch_bounds__(512, 8) void phi_pool(
    const float* __restrict__ dm, const int* __restrict__ lengths,
    const float2* __restrict__ table2, const float* __restrict__ tsort,
    float* __restrict__ pooled) {
  __shared__ float2 ab_s[SEGS * 64];   // 33,280 B -> 4 blocks/CU
  const int chunk = blockIdx.x;   // 0..15
  const int h     = blockIdx.y;   // channel half
  const int b     = blockIdx.z;   // batch
  const int tid = threadIdx.x;
  const int lane = tid & 63, w = tid >> 6;

  const int len = lengths[b];
  // block-uniform early exit: no primary row (8c) and no mirror row (247-8c)
  if (8 * chunk > len - 2 && 247 - 8 * chunk > len - 2) return;

  const float2* tg = table2 + h * SEGS * 64;
  for (int i = tid; i < SEGS * 64; i += 512) ab_s[i] = tg[i];
  __syncthreads();

  const float tv = tsort[lane];      // breakpoint in register, one per lane
  const float* dmb = dm + (size_t)b * (NN * NN);
  float acc = 0.f;

  const int rA = chunk * 8 + w;      // 0..127
  const int rB = 254 - rA;           // 127..254
  // issue both full-row loads up-front (always address-valid)
  const float4 fA = ((const float4*)(dmb + rA * NN))[lane];
  const float4 fB = ((const float4*)(dmb + rB * NN))[lane];
  if (rA <= len - 2) do_row(fA, rA, len, tv, lane, ab_s, acc);
  if (rB != rA && rB <= len - 2) do_row(fB, rB, len, tv, lane, ab_s, acc);

  atomicAdd(&pooled[b * PHI2 + h * 64 + lane], acc);
}

// ---------------- Kernel C: rho MLP ----------------
// grid: 32 blocks (one per batch), 256 threads. Weight layers staged
// through one reused 128 KB LDS buffer with independent float4 loads.
__global__ __launch_bounds__(256) void rho_mlp(
    const float* __restrict__ pooled,
    const float* __restrict__ W3, const float* __restrict__ b3,
    const float* __restrict__ W4, const float* __restrict__ b4,
    const float* __restrict__ W5, const float* __restrict__ b5,
    float* __restrict__ out) {
  __shared__ float w_s[128 * 256];     // 128 KB, reused per layer
  __shared__ float p_s[128], r1_s[256], r2_s[128];
  const int b = blockIdx.x, tid = threadIdx.x;
  float4* wsv = (float4*)w_s;
  {
    const float4* w3v = (const float4*)W3;
    for (int i = tid; i < 8192; i += 256) wsv[i] = w3v[i];
  }
  if (tid < 128) p_s[tid] = pooled[b * 128 + tid];
  __syncthreads();
  {
    float acc = b3[tid];
#pragma unroll 8
    for (int k = 0; k < 128; ++k) acc = fmaf(p_s[k], w_s[k * 256 + tid], acc);
    r1_s[tid] = fmaxf(acc, 0.f);
  }
  __syncthreads();
  {
    const float4* w4v = (const float4*)W4;
    for (int i = tid; i < 8192; i += 256) wsv[i] = w4v[i];
  }
  __syncthreads();
  if (tid < 128) {
    float acc = b4[tid];
#pragma unroll 8
    for (int k = 0; k < 256; ++k) acc = fmaf(r1_s[k], w_s[k * 128 + tid], acc);
    r2_s[tid] = fmaxf(acc, 0.f);
  }
  __syncthreads();
  {
    const float4* w5v = (const float4*)W5;
    for (int i = tid; i < 2048; i += 256) wsv[i] = w5v[i];
  }
  __syncthreads();
  if (tid < 64) {
    float acc = b5[tid];
#pragma unroll 8
    for (int k = 0; k < 128; ++k) acc = fmaf(r2_s[k], w_s[k * 64 + tid], acc);
    out[b * 64 + tid] = acc;
  }
}

extern "C" void kernel_launch(void* const* d_in, const int* in_sizes, int n_in,
                              void* d_out, int out_size, void* d_ws, size_t ws_size,
                              hipStream_t stream) {
  const float* dm      = (const float*)d_in[0];
  const int*   lengths = (const int*)d_in[1];
  const float* W1 = (const float*)d_in[2];
  const float* b1 = (const float*)d_in[3];
  const float* W2 = (const float*)d_in[4];
  const float* b2 = (const float*)d_in[5];
  const float* W3 = (const float*)d_in[6];
  const float* b3 = (const float*)d_in[7];
  const float* W4 = (const float*)d_in[8];
  const float* b4 = (const float*)d_in[9];
  const float* W5 = (const float*)d_in[10];
  const float* b5 = (const float*)d_in[11];

  float* ws = (float*)d_ws;
  float2* table2 = (float2*)ws;          // 2*65*64 float2 = 16640 floats
  float* tsort   = ws + 16640;           // 64
  float* pooled  = ws + 16704;           // 32*128 = 4096

  build_tables<<<SEGS, 128, 0, stream>>>(W1, b1, W2, b2, table2, tsort, pooled);
  phi_pool<<<dim3(16, 2, NB), 512, 0, stream>>>(dm, lengths, table2, tsort, pooled);
  rho_mlp<<<NB, 256, 0, stream>>>(pooled, W3, b3, W4, b4, W5, b5, (float*)d_out);
}